// Round 4
// baseline (178.466 us; speedup 1.0000x reference)
//
#include <hip/hip_runtime.h>
#include <hip/hip_cooperative_groups.h>
#include <math.h>

namespace cg = cooperative_groups;

#define BIGV 10000000000.0f
#define WA   0.096f

// min over j of [lab[j]==L ? 0 : BIG] + (WA*(i-j))^2 from a 64-bit seed mask.
__device__ __forceinline__ float seed_dist2(unsigned long long mask, int i) {
    const unsigned long long mr = mask >> i;          // seeds at j >= i
    const unsigned long long ml = mask << (63 - i);   // seeds at j <= i
    const int dr = mr ? __builtin_ctzll(mr) : 1000;
    const int dl = ml ? __builtin_clzll(ml) : 1000;
    const int d  = dr < dl ? dr : dl;
    const float t = WA * (float)d;
    return (d > 63) ? BIGV : t * t;
}

// Single cooperative kernel, 512 blocks x 256 threads (2 blocks/CU co-resident:
// 48 KB LDS -> 96/160 KB, 8/32 waves, ~68 VGPR).
// Phase 1: x-pass (ballot) + z-pass  -> D[b*3+L][z][y][x] in ws
// Phase 2: y-pass + penalty epilogue -> partials[block]
// Phase 3: block 0 tree-reduces 512 partials -> out[0] (no memset, no atomics)
__global__ __launch_bounds__(256) void fused_kernel(const float* __restrict__ x,
                                                    const int* __restrict__ lab,
                                                    float* __restrict__ D,
                                                    float* __restrict__ partials,
                                                    float* __restrict__ out) {
    cg::grid_group grid = cg::this_grid();
    const int bid  = blockIdx.x;           // 0..511
    const int lane = threadIdx.x & 63;
    const int wv   = threadIdx.x >> 6;

    __shared__ float sm[3][64][64];        // 48 KB, reused across phases

    // ---------------- Phase 1: block = (ys, b, zq) ----------------
    {
        const int ys = bid & 63, b = (bid >> 6) & 1, zq = bid >> 7;

        const int* lp = lab + b * 262144 + ys * 64;
        for (int z = wv * 16, e = z + 16; z < e; ++z) {
            const int lv = lp[z * 4096 + lane];
            sm[0][z][lane] = seed_dist2(__ballot(lv == 0), lane);
            sm[1][z][lane] = seed_dist2(__ballot(lv == 1), lane);
            sm[2][z][lane] = seed_dist2(__ballot(lv == 2), lane);
        }
        __syncthreads();

        const int i0 = zq * 16 + wv * 4;   // 4 output-z rows per wave
        float m0[4], m1[4], m2[4];
#pragma unroll
        for (int ii = 0; ii < 4; ++ii) m0[ii] = m1[ii] = m2[ii] = __builtin_inff();

        for (int j = 0; j < 64; ++j) {
            const float a0 = sm[0][j][lane];
            const float a1 = sm[1][j][lane];
            const float a2 = sm[2][j][lane];
            const float fb = (float)(i0 - j);
#pragma unroll
            for (int ii = 0; ii < 4; ++ii) {
                const float t = WA * (fb + (float)ii);
                m0[ii] = fminf(m0[ii], __builtin_fmaf(t, t, a0));
                m1[ii] = fminf(m1[ii], __builtin_fmaf(t, t, a1));
                m2[ii] = fminf(m2[ii], __builtin_fmaf(t, t, a2));
            }
        }

        float* Dp = D + b * 3 * 262144 + ys * 64;
#pragma unroll
        for (int ii = 0; ii < 4; ++ii) {
            const int zo = (i0 + ii) * 4096 + lane;
            Dp[zo]              = m0[ii];
            Dp[262144 + zo]     = m1[ii];
            Dp[2 * 262144 + zo] = m2[ii];
        }
    }

    grid.sync();

    // ---------------- Phase 2: block = (z, b, yq) ----------------
    {
        const int z = bid & 63, b = (bid >> 6) & 1, yq = bid >> 7;

        const float4* Dp4 = (const float4*)(D + b * 3 * 262144 + z * 4096);
        float4* s4 = (float4*)&sm[0][0][0];
        for (int t = threadIdx.x; t < 1024; t += 256) {
            s4[t]        = Dp4[t];
            s4[1024 + t] = Dp4[65536 + t];
            s4[2048 + t] = Dp4[131072 + t];
        }
        __syncthreads();

        const int i0 = yq * 16 + wv * 4;   // 4 output-y rows per wave
        float m0[4], m1[4], m2[4];
#pragma unroll
        for (int ii = 0; ii < 4; ++ii) m0[ii] = m1[ii] = m2[ii] = __builtin_inff();

        for (int j = 0; j < 64; ++j) {
            const float a0 = sm[0][j][lane];
            const float a1 = sm[1][j][lane];
            const float a2 = sm[2][j][lane];
            const float fb = (float)(i0 - j);
#pragma unroll
            for (int ii = 0; ii < 4; ++ii) {
                const float t = WA * (fb + (float)ii);
                m0[ii] = fminf(m0[ii], __builtin_fmaf(t, t, a0));
                m1[ii] = fminf(m1[ii], __builtin_fmaf(t, t, a1));
                m2[ii] = fminf(m2[ii], __builtin_fmaf(t, t, a2));
            }
        }

        float part = 0.0f;
#pragma unroll
        for (int ii = 0; ii < 4; ++ii) {
            const int yy  = i0 + ii;
            const int off = z * 4096 + yy * 64 + lane;
            const int lv  = lab[b * 262144 + off];
            const float x1 = x[(b * 3 + 1) * 262144 + off];
            const float x2 = x[(b * 3 + 2) * 262144 + off];
            const float d0  = (lv == 0) ? BIGV : m0[ii];
            const float d1  = (lv == 1) ? BIGV : m1[ii];
            const float d2m = (lv == 2) ? BIGV : m2[ii];
            const float dt  = sqrtf(fminf(d0, fminf(d1, d2m))) + 1.0f;
            const float t1  = (lv == 1) ? (1.0f - x1) : x1;
            const float t2  = (lv == 2) ? (1.0f - x2) : x2;
            part += (t1 + t2) * dt;
        }

#pragma unroll
        for (int o = 32; o; o >>= 1) part += __shfl_down(part, o);

        __syncthreads();                   // sm reads done; reuse as scratch
        if (lane == 0) sm[0][0][wv] = part;
        __syncthreads();
        if (threadIdx.x == 0)
            partials[bid] = sm[0][0][0] + sm[0][0][1] + sm[0][0][2] + sm[0][0][3];
    }

    grid.sync();

    // ---------------- Phase 3: block 0 reduces 512 partials ----------------
    if (bid == 0) {
        float v = partials[threadIdx.x] + partials[threadIdx.x + 256];
#pragma unroll
        for (int o = 32; o; o >>= 1) v += __shfl_down(v, o);
        if (lane == 0) sm[0][0][8 + wv] = v;
        __syncthreads();
        if (threadIdx.x == 0)
            out[0] = (sm[0][0][8] + sm[0][0][9] + sm[0][0][10] + sm[0][0][11])
                         * (1.0f / 1048576.0f) + 1e-5f;
    }
}

extern "C" void kernel_launch(void* const* d_in, const int* in_sizes, int n_in,
                              void* d_out, int out_size, void* d_ws, size_t ws_size,
                              hipStream_t stream) {
    const float* x = (const float*)d_in[0];   // (2,3,64,64,64) fp32
    const int*   y = (const int*)d_in[1];     // (2,1,64,64,64) int32
    float* D        = (float*)d_ws;           // 6 * 262144 floats
    float* partials = D + 6 * 262144;         // 512 floats
    float* out      = (float*)d_out;

    void* args[] = {(void*)&x, (void*)&y, (void*)&D, (void*)&partials, (void*)&out};
    hipLaunchCooperativeKernel((const void*)fused_kernel, dim3(512), dim3(256),
                               args, 0, stream);
}

// Round 5
// 101.629 us; speedup vs baseline: 1.7561x; 1.7561x over previous
//
#include <hip/hip_runtime.h>
#include <math.h>

#define BIGV 10000000000.0f
#define WA   0.096f

// min over j of [lab[j]==L ? 0 : BIG] + (WA*(i-j))^2  ==  (WA*dist_to_nearest_seed)^2
// computed from a 64-bit seed mask via ctz/clz. Exact match to brute force.
__device__ __forceinline__ float seed_dist2(unsigned long long mask, int i) {
    const unsigned long long mr = mask >> i;          // seeds at j >= i
    const unsigned long long ml = mask << (63 - i);   // seeds at j <= i
    const int dr = mr ? __builtin_ctzll(mr) : 1000;
    const int dl = ml ? __builtin_clzll(ml) : 1000;
    const int d  = dr < dl ? dr : dl;
    const float t = WA * (float)d;
    return (d > 63) ? BIGV : t * t;
}

// Kernel A: x-pass (ballot) + z-pass for all 3 labels, per (b, y) slice.
// Grid (y=64, b=2, zq=4), 256 threads. D layout: [b*3+L][z][y][x] fp32.
// Also initializes out[0] = 1e-5 (stream order: A completes before B starts).
__global__ __launch_bounds__(256) void pass_xz_kernel(const int* __restrict__ lab,
                                                      float* __restrict__ D,
                                                      float* __restrict__ out) {
    if (blockIdx.x == 0 && blockIdx.y == 0 && blockIdx.z == 0 && threadIdx.x == 0)
        out[0] = 1e-5f;

    const int ys = blockIdx.x, b = blockIdx.y, zq = blockIdx.z;
    const int lane = threadIdx.x & 63;
    const int wv   = threadIdx.x >> 6;

    __shared__ float sm[3][64][64];                  // [L][z][x], 48 KB

    const int* lp = lab + b * 262144 + ys * 64;
    for (int z = wv * 16, e = z + 16; z < e; ++z) {
        const int lv = lp[z * 4096 + lane];
        sm[0][z][lane] = seed_dist2(__ballot(lv == 0), lane);
        sm[1][z][lane] = seed_dist2(__ballot(lv == 1), lane);
        sm[2][z][lane] = seed_dist2(__ballot(lv == 2), lane);
    }
    __syncthreads();

    const int i0 = zq * 16 + wv * 4;                 // 4 output-z rows per wave
    float m0[4], m1[4], m2[4];
#pragma unroll
    for (int ii = 0; ii < 4; ++ii) m0[ii] = m1[ii] = m2[ii] = __builtin_inff();

    for (int j = 0; j < 64; ++j) {
        const float a0 = sm[0][j][lane];
        const float a1 = sm[1][j][lane];
        const float a2 = sm[2][j][lane];
        const float fb = (float)(i0 - j);
#pragma unroll
        for (int ii = 0; ii < 4; ++ii) {
            const float t = WA * (fb + (float)ii);
            m0[ii] = fminf(m0[ii], __builtin_fmaf(t, t, a0));
            m1[ii] = fminf(m1[ii], __builtin_fmaf(t, t, a1));
            m2[ii] = fminf(m2[ii], __builtin_fmaf(t, t, a2));
        }
    }

    float* Dp = D + b * 3 * 262144 + ys * 64;
#pragma unroll
    for (int ii = 0; ii < 4; ++ii) {
        const int zo = (i0 + ii) * 4096 + lane;
        Dp[zo]              = m0[ii];
        Dp[262144 + zo]     = m1[ii];
        Dp[2 * 262144 + zo] = m2[ii];
    }
}

// Kernel B: y-pass + penalty epilogue + reduction, per (b, z) slice.
// Grid (z=64, b=2, yq=4), 256 threads.
__global__ __launch_bounds__(256) void pass_y_kernel(const float* __restrict__ x,
                                                     const int* __restrict__ lab,
                                                     const float* __restrict__ D,
                                                     float* __restrict__ out) {
    const int z = blockIdx.x, b = blockIdx.y, yq = blockIdx.z;
    const int lane = threadIdx.x & 63;
    const int wv   = threadIdx.x >> 6;

    __shared__ float sm[3][64][64];                  // [L][y][x], 48 KB
    {
        const float4* Dp4 = (const float4*)(D + b * 3 * 262144 + z * 4096);
        float4* s4 = (float4*)&sm[0][0][0];
        for (int t = threadIdx.x; t < 1024; t += 256) {
            s4[t]        = Dp4[t];
            s4[1024 + t] = Dp4[65536 + t];
            s4[2048 + t] = Dp4[131072 + t];
        }
    }

    // Prefetch epilogue inputs before the compute loop (hide global latency).
    const int i0 = yq * 16 + wv * 4;                 // 4 output-y rows per wave
    int   lv[4];
    float x1[4], x2[4];
#pragma unroll
    for (int ii = 0; ii < 4; ++ii) {
        const int off = z * 4096 + (i0 + ii) * 64 + lane;
        lv[ii] = lab[b * 262144 + off];
        x1[ii] = x[(b * 3 + 1) * 262144 + off];
        x2[ii] = x[(b * 3 + 2) * 262144 + off];
    }
    __syncthreads();

    float m0[4], m1[4], m2[4];
#pragma unroll
    for (int ii = 0; ii < 4; ++ii) m0[ii] = m1[ii] = m2[ii] = __builtin_inff();

    for (int j = 0; j < 64; ++j) {
        const float a0 = sm[0][j][lane];
        const float a1 = sm[1][j][lane];
        const float a2 = sm[2][j][lane];
        const float fb = (float)(i0 - j);
#pragma unroll
        for (int ii = 0; ii < 4; ++ii) {
            const float t = WA * (fb + (float)ii);
            m0[ii] = fminf(m0[ii], __builtin_fmaf(t, t, a0));
            m1[ii] = fminf(m1[ii], __builtin_fmaf(t, t, a1));
            m2[ii] = fminf(m2[ii], __builtin_fmaf(t, t, a2));
        }
    }

    float part = 0.0f;
#pragma unroll
    for (int ii = 0; ii < 4; ++ii) {
        const float d0  = (lv[ii] == 0) ? BIGV : m0[ii];
        const float d1  = (lv[ii] == 1) ? BIGV : m1[ii];
        const float d2m = (lv[ii] == 2) ? BIGV : m2[ii];
        const float dt  = sqrtf(fminf(d0, fminf(d1, d2m))) + 1.0f;
        const float t1  = (lv[ii] == 1) ? (1.0f - x1[ii]) : x1[ii];
        const float t2  = (lv[ii] == 2) ? (1.0f - x2[ii]) : x2[ii];
        part += (t1 + t2) * dt;
    }

#pragma unroll
    for (int o = 32; o; o >>= 1) part += __shfl_down(part, o);
    if (lane == 0)
        atomicAdd(out, part * (1.0f / 1048576.0f));
}

extern "C" void kernel_launch(void* const* d_in, const int* in_sizes, int n_in,
                              void* d_out, int out_size, void* d_ws, size_t ws_size,
                              hipStream_t stream) {
    const float* x = (const float*)d_in[0];   // (2,3,64,64,64) fp32
    const int*   y = (const int*)d_in[1];     // (2,1,64,64,64) int32
    float* D   = (float*)d_ws;                // 6 * 262144 floats
    float* out = (float*)d_out;

    pass_xz_kernel<<<dim3(64, 2, 4), 256, 0, stream>>>(y, D, out);
    pass_y_kernel<<<dim3(64, 2, 4), 256, 0, stream>>>(x, y, D, out);
}

// Round 6
// 99.136 us; speedup vs baseline: 1.8002x; 1.0251x over previous
//
#include <hip/hip_runtime.h>
#include <math.h>

#define BIGV 10000000000.0f
#define WA   0.096f
#define ABSENT 16000   // sentinel: "no seed" (real max d2 = 3*63^2 = 11907)

typedef short short2v __attribute__((ext_vector_type(2)));

__device__ __forceinline__ short2v pack2(int a, int b) {
    short2v r; r.x = (short)a; r.y = (short)b; return r;
}

// nearest-seed distance^2 (integer, exact) along x from a 64-bit seed mask.
__device__ __forceinline__ short seed_d2_i16(unsigned long long mask, int i) {
    const unsigned long long mr = mask >> i;          // seeds at j >= i
    const unsigned long long ml = mask << (63 - i);   // seeds at j <= i
    const int dr = mr ? __builtin_ctzll(mr) : 127;
    const int dl = ml ? __builtin_clzll(ml) : 127;
    const int d  = dr < dl ? dr : dl;
    return (short)(d > 63 ? ABSENT : d * d);
}

// Kernel A: x-pass (ballot) + z-pass, integer d2 domain, all 3 labels.
// Grid (y=64, b=2, zq=4), 256 threads. D layout: [b*3+L][z][y][x] uint16.
// Also initializes out[0] = 1e-5 (stream order: A completes before B's atomics).
__global__ __launch_bounds__(256) void pass_xz_kernel(const int* __restrict__ lab,
                                                      unsigned short* __restrict__ D,
                                                      float* __restrict__ out) {
    if (blockIdx.x == 0 && blockIdx.y == 0 && blockIdx.z == 0 && threadIdx.x == 0)
        out[0] = 1e-5f;

    const int ys = blockIdx.x, b = blockIdx.y, zq = blockIdx.z;
    const int lane = threadIdx.x & 63;
    const int wv   = threadIdx.x >> 6;

    __shared__ short sm[3][64][64];                  // [L][z][x], 24 KB

    const int* lp = lab + b * 262144 + ys * 64;
    for (int z = wv * 16, e = z + 16; z < e; ++z) {
        const int lv = lp[z * 4096 + lane];
        sm[0][z][lane] = seed_d2_i16(__ballot(lv == 0), lane);
        sm[1][z][lane] = seed_d2_i16(__ballot(lv == 1), lane);
        sm[2][z][lane] = seed_d2_i16(__ballot(lv == 2), lane);
    }
    __syncthreads();

    const int i0 = zq * 16 + wv * 4;                 // 4 output-z rows per wave
    // packed accumulators: pair0 = rows {i0, i0+1}, pair1 = rows {i0+2, i0+3}
    short2v mA0 = {32767, 32767}, mA1 = mA0;
    short2v mB0 = mA0, mB1 = mA0, mC0 = mA0, mC1 = mA0;

    for (int j = 0; j < 64; ++j) {
        const short a0 = sm[0][j][lane];
        const short a1 = sm[1][j][lane];
        const short a2 = sm[2][j][lane];
        const short2v a0p = {a0, a0}, a1p = {a1, a1}, a2p = {a2, a2};
        const int dz = i0 - j;                        // wave-uniform -> SALU
        const short2v d2p0 = pack2(dz * dz, (dz + 1) * (dz + 1));
        const short2v d2p1 = pack2((dz + 2) * (dz + 2), (dz + 3) * (dz + 3));
        mA0 = __builtin_elementwise_min(mA0, (short2v)(a0p + d2p0));
        mA1 = __builtin_elementwise_min(mA1, (short2v)(a0p + d2p1));
        mB0 = __builtin_elementwise_min(mB0, (short2v)(a1p + d2p0));
        mB1 = __builtin_elementwise_min(mB1, (short2v)(a1p + d2p1));
        mC0 = __builtin_elementwise_min(mC0, (short2v)(a2p + d2p0));
        mC1 = __builtin_elementwise_min(mC1, (short2v)(a2p + d2p1));
    }

    // coalesced 16-bit stores (lanes = consecutive x)
    unsigned short* Dp = D + b * 3 * 262144 + ys * 64 + lane;
    const int r0 = i0 * 4096;
    Dp[r0]                       = (unsigned short)mA0.x;
    Dp[r0 + 4096]                = (unsigned short)mA0.y;
    Dp[r0 + 2 * 4096]            = (unsigned short)mA1.x;
    Dp[r0 + 3 * 4096]            = (unsigned short)mA1.y;
    Dp[262144 + r0]              = (unsigned short)mB0.x;
    Dp[262144 + r0 + 4096]       = (unsigned short)mB0.y;
    Dp[262144 + r0 + 2 * 4096]   = (unsigned short)mB1.x;
    Dp[262144 + r0 + 3 * 4096]   = (unsigned short)mB1.y;
    Dp[524288 + r0]              = (unsigned short)mC0.x;
    Dp[524288 + r0 + 4096]       = (unsigned short)mC0.y;
    Dp[524288 + r0 + 2 * 4096]   = (unsigned short)mC1.x;
    Dp[524288 + r0 + 3 * 4096]   = (unsigned short)mC1.y;
}

// Kernel B: y-pass (integer) + penalty epilogue + reduction, per (b, z) slice.
// Grid (z=64, b=2, yq=4), 256 threads.
__global__ __launch_bounds__(256) void pass_y_kernel(const float* __restrict__ x,
                                                     const int* __restrict__ lab,
                                                     const unsigned short* __restrict__ D,
                                                     float* __restrict__ out) {
    const int z = blockIdx.x, b = blockIdx.y, yq = blockIdx.z;
    const int lane = threadIdx.x & 63;
    const int wv   = threadIdx.x >> 6;

    __shared__ short sm[3][64][64];                  // [L][y][x], 24 KB
    {
        // each L-plane at this z: 4096 shorts = 512 uint4, 16B-aligned
        const uint4* Dp4 = (const uint4*)(D + b * 3 * 262144 + z * 4096);
        uint4* s4 = (uint4*)&sm[0][0][0];
        for (int t = threadIdx.x; t < 512; t += 256) {
            s4[t]        = Dp4[t];
            s4[512 + t]  = Dp4[32768 + t];           // +262144 shorts
            s4[1024 + t] = Dp4[65536 + t];
        }
    }

    // Prefetch epilogue inputs before the compute loop (hide global latency).
    const int i0 = yq * 16 + wv * 4;                 // 4 output-y rows per wave
    int   lv[4];
    float x1[4], x2[4];
#pragma unroll
    for (int ii = 0; ii < 4; ++ii) {
        const int off = z * 4096 + (i0 + ii) * 64 + lane;
        lv[ii] = lab[b * 262144 + off];
        x1[ii] = x[(b * 3 + 1) * 262144 + off];
        x2[ii] = x[(b * 3 + 2) * 262144 + off];
    }
    __syncthreads();

    short2v mA0 = {32767, 32767}, mA1 = mA0;
    short2v mB0 = mA0, mB1 = mA0, mC0 = mA0, mC1 = mA0;

    for (int j = 0; j < 64; ++j) {
        const short a0 = sm[0][j][lane];
        const short a1 = sm[1][j][lane];
        const short a2 = sm[2][j][lane];
        const short2v a0p = {a0, a0}, a1p = {a1, a1}, a2p = {a2, a2};
        const int dy = i0 - j;
        const short2v d2p0 = pack2(dy * dy, (dy + 1) * (dy + 1));
        const short2v d2p1 = pack2((dy + 2) * (dy + 2), (dy + 3) * (dy + 3));
        mA0 = __builtin_elementwise_min(mA0, (short2v)(a0p + d2p0));
        mA1 = __builtin_elementwise_min(mA1, (short2v)(a0p + d2p1));
        mB0 = __builtin_elementwise_min(mB0, (short2v)(a1p + d2p0));
        mB1 = __builtin_elementwise_min(mB1, (short2v)(a1p + d2p1));
        mC0 = __builtin_elementwise_min(mC0, (short2v)(a2p + d2p0));
        mC1 = __builtin_elementwise_min(mC1, (short2v)(a2p + d2p1));
    }

    const int g0[4] = {mA0.x, mA0.y, mA1.x, mA1.y};
    const int g1[4] = {mB0.x, mB0.y, mB1.x, mB1.y};
    const int g2[4] = {mC0.x, mC0.y, mC1.x, mC1.y};

    float part = 0.0f;
#pragma unroll
    for (int ii = 0; ii < 4; ++ii) {
        const int e0 = (lv[ii] == 0) ? (1 << 20) : g0[ii];
        const int e1 = (lv[ii] == 1) ? (1 << 20) : g1[ii];
        const int e2 = (lv[ii] == 2) ? (1 << 20) : g2[ii];
        const int dm = min(e0, min(e1, e2));
        const float d2f = (dm >= ABSENT) ? BIGV : (float)dm * (WA * WA);
        const float dt  = sqrtf(d2f) + 1.0f;
        const float t1  = (lv[ii] == 1) ? (1.0f - x1[ii]) : x1[ii];
        const float t2  = (lv[ii] == 2) ? (1.0f - x2[ii]) : x2[ii];
        part += (t1 + t2) * dt;
    }

#pragma unroll
    for (int o = 32; o; o >>= 1) part += __shfl_down(part, o);
    if (lane == 0)
        atomicAdd(out, part * (1.0f / 1048576.0f));
}

extern "C" void kernel_launch(void* const* d_in, const int* in_sizes, int n_in,
                              void* d_out, int out_size, void* d_ws, size_t ws_size,
                              hipStream_t stream) {
    const float* x = (const float*)d_in[0];   // (2,3,64,64,64) fp32
    const int*   y = (const int*)d_in[1];     // (2,1,64,64,64) int32
    unsigned short* D = (unsigned short*)d_ws; // 6 * 262144 uint16 = 3 MB
    float* out = (float*)d_out;

    pass_xz_kernel<<<dim3(64, 2, 4), 256, 0, stream>>>(y, D, out);
    pass_y_kernel<<<dim3(64, 2, 4), 256, 0, stream>>>(x, y, D, out);
}